// Round 9
// baseline (212.473 us; speedup 1.0000x reference)
//
#include <hip/hip_runtime.h>

// S4D kernel materialization:
//   dt = exp(log_dt[h]) ; A = -exp(log_A_real) + i*A_imag
//   dtA = A*dt ; w = exp(dtA) ; Cc = C*(w-1)/A
//   K[h,l] = 2 * Re( sum_n Cc[h,n] * w[h,n]^l )
//
// R9 = DIAGNOSTIC on the R8 structure (BLK=512, mode-split, J=16).
// Three rounds of structural edits were neutral and the kernel runs below
// the harness's 41.5us poison fills, so it has been invisible to rocprof.
// REPS=16 repeats the main loop (opaque asm blocks CSE; store scales by
// 1/16) to force top-1 visibility and capture VGPR/Occupancy/VALUBusy,
// resolving: (a) VGPR>64 broke 8-wave-block occupancy, (b) kernel already
// at pipe bound (~13us, floor ~65), (c) structural stall.

static __device__ __forceinline__ float2 cmul(float2 a, float2 b) {
    return make_float2(fmaf(a.x, b.x, -(a.y * b.y)),
                       fmaf(a.x, b.y,   a.y * b.x));
}

template <int N2, int CPB, int J, int REPS>
__global__ __launch_bounds__(2 * CPB, 8) void s4d_kernel(
    const float* __restrict__ C,
    const float* __restrict__ log_dt,
    const float* __restrict__ log_A_real,
    const float* __restrict__ A_imag,
    float* __restrict__ K,
    int L)
{
    constexpr int MPG = N2 / 2;          // modes per wave-group
    __shared__ float4 s_lop[N2][16];     // (lo.x, lo.y, (lo*W).x, (lo*W).y), lo = 2Cc*w^(lbase+k)
    __shared__ float4 s_hip[N2][16];     // ((w^16)^k re, im, 2Re(W), -|W|^2)
    __shared__ float4 s_part[J / 4][CPB];// group-1 partial sums

    const int h = blockIdx.x;
    const int y = blockIdx.y;
    const int lbase = y * (CPB * J);
    const int t = threadIdx.x;

    // ---- Parallel setup: thread t (0..511) builds entry (n = t>>4, k = t&15) ----
    {
        const int n = t >> 4;            // 0..31
        const int k = t & 15;

        const float dt  = expf(log_dt[h]);
        const float Are = -expf(log_A_real[h * N2 + n]);
        const float Aim = A_imag[h * N2 + n];
        const float dre = Are * dt;
        const float dim = Aim * dt;      // |dim| <= ~9.7 rad: fast sincos path
        float sw, cw;
        sincosf(dim, &sw, &cw);
        const float er = expf(dre);
        const float2 w = make_float2(er * cw, er * sw);
        // 2*Cc = 2*C*(w-1)/A
        const float nre = w.x - 1.0f;
        const float nim = w.y;
        const float inv = 1.0f / (Are * Are + Aim * Aim);
        const float cc  = 2.0f * C[h * N2 + n];
        const float2 c  = make_float2(cc * ((nre * Are + nim * Aim) * inv),
                                      cc * ((nim * Are - nre * Aim) * inv));
        // powers of w by squaring
        const float2 w2   = cmul(w,    w);
        const float2 w4   = cmul(w2,   w2);
        const float2 w8   = cmul(w4,   w4);
        const float2 w16  = cmul(w8,   w8);
        const float2 w32  = cmul(w16,  w16);
        const float2 w64  = cmul(w32,  w32);
        const float2 w128 = cmul(w64,  w64);
        const float2 W    = cmul(w128, w128);   // w^256 == w^CPB
        const float aW = W.x + W.x;
        const float bW = -fmaf(W.x, W.x, W.y * W.y);

        const float2 ONE = make_float2(1.0f, 0.0f);
        // w^k, k<16: product of selected {w,w2,w4,w8}
        float2 pk = (k & 1) ? w : ONE;
        pk = cmul(pk, (k & 2) ? w2 : ONE);
        pk = cmul(pk, (k & 4) ? w4 : ONE);
        pk = cmul(pk, (k & 8) ? w8 : ONE);
        // (w^16)^k: product of selected {w16,w32,w64,w128}
        float2 qk = (k & 1) ? w16 : ONE;
        qk = cmul(qk, (k & 2) ? w32  : ONE);
        qk = cmul(qk, (k & 4) ? w64  : ONE);
        qk = cmul(qk, (k & 8) ? w128 : ONE);

        // w^lbase = W^(J*y), block-uniform binary pow (no-op when y==0)
        float2 P = ONE;
        {
            float2 base = W;
            int ee = J * y;
            while (ee) { if (ee & 1) P = cmul(P, base); base = cmul(base, base); ee >>= 1; }
        }

        const float2 lo  = cmul(cmul(c, P), pk);   // 2Cc * w^(lbase+k)
        const float2 lo2 = cmul(lo, W);
        s_lop[n][k] = make_float4(lo.x, lo.y, lo2.x, lo2.y);
        s_hip[n][k] = make_float4(qk.x, qk.y, aW, bW);
    }
    __syncthreads();

    float acc[J];
#pragma unroll
    for (int j = 0; j < J; ++j) acc[j] = 0.0f;

    const int col = t & (CPB - 1);       // sample column 0..255
    const int g   = t / CPB;             // wave-group 0/1
    const int tlo = col & 15;
    const int thi = col >> 4;
    const int nb  = g * MPG;

    for (int r = 0; r < REPS; ++r) {
        // Opaque indices: force each rep to re-execute loads + math (no CSE).
        int tlo2 = tlo, thi2 = thi;
        asm volatile("" : "+v"(tlo2), "+v"(thi2));

#pragma unroll 2
        for (int nn = 0; nn < MPG; ++nn) {
            const float4 lp = s_lop[nb + nn][tlo2];
            const float4 hp = s_hip[nb + nn][thi2];

            float x0 = fmaf(lp.x, hp.x, -(lp.y * hp.y));   // Re(2Cc w^(lbase+col))
            float x1 = fmaf(lp.z, hp.x, -(lp.w * hp.y));   // Re(... * W)
            acc[0] += x0;
            acc[1] += x1;
#pragma unroll
            for (int j = 2; j < J; ++j) {
                const float x2 = fmaf(hp.z, x1, hp.w * x0);  // 2Re(W)x1 - |W|^2 x0
                acc[j] += x2;
                x0 = x1;
                x1 = x2;
            }
        }
    }

    const float scale = 1.0f / (float)REPS;

    // ---- Cross-group reduction + store ----
    if (g == 1) {
#pragma unroll
        for (int q = 0; q < J / 4; ++q)
            s_part[q][col] = make_float4(acc[4*q], acc[4*q+1], acc[4*q+2], acc[4*q+3]);
    }
    __syncthreads();
    if (g == 0) {
        float* __restrict__ outp = K + (size_t)h * (size_t)L + lbase + col;
#pragma unroll
        for (int q = 0; q < J / 4; ++q) {
            const float4 p = s_part[q][col];
            const float r0 = (acc[4*q]     + p.x) * scale;
            const float r1 = (acc[4*q + 1] + p.y) * scale;
            const float r2 = (acc[4*q + 2] + p.z) * scale;
            const float r3 = (acc[4*q + 3] + p.w) * scale;
            const int l0 = lbase + (4*q) * CPB + col;
            if (l0 < L)             outp[(size_t)(4*q)     * CPB] = r0;
            if (l0 + CPB < L)       outp[(size_t)(4*q + 1) * CPB] = r1;
            if (l0 + 2 * CPB < L)   outp[(size_t)(4*q + 2) * CPB] = r2;
            if (l0 + 3 * CPB < L)   outp[(size_t)(4*q + 3) * CPB] = r3;
        }
    }
}

extern "C" void kernel_launch(void* const* d_in, const int* in_sizes, int n_in,
                              void* d_out, int out_size, void* d_ws, size_t ws_size,
                              hipStream_t stream)
{
    const float* C          = (const float*)d_in[0];
    const float* log_dt     = (const float*)d_in[1];
    const float* log_A_real = (const float*)d_in[2];
    const float* A_imag     = (const float*)d_in[3];
    float* K = (float*)d_out;

    const int H   = in_sizes[1];           // 1024
    const int N2v = in_sizes[0] / H;       // 32
    const int L   = out_size / H;          // 4096
    constexpr int CPB  = 256;              // sample columns per block
    constexpr int J    = 16;               // samples per column per block
    constexpr int REPS = 16;               // DIAGNOSTIC: x16 main loop for rocprof visibility
    const int gy = (L + CPB * J - 1) / (CPB * J);   // 1 for L=4096

    if (N2v != 32) return;
    dim3 grid((unsigned)H, (unsigned)gy);
    s4d_kernel<32, CPB, J, REPS><<<grid, 2 * CPB, 0, stream>>>(
        C, log_dt, log_A_real, A_imag, K, L);
}

// Round 10
// 75.810 us; speedup vs baseline: 2.8027x; 2.8027x over previous
//
#include <hip/hip_runtime.h>

// S4D kernel materialization:
//   dt = exp(log_dt[h]) ; A = -exp(log_A_real) + i*A_imag
//   dtA = A*dt ; w = exp(dtA) ; Cc = C*(w-1)/A
//   K[h,l] = 2 * Re( sum_n Cc[h,n] * w[h,n]^l )
//
// R9 diagnostic: VALU-issue-bound at 90% busy (VGPR=24, no spill, conflicts
// negligible; main pass ~11us, kernel ~13us, bench floor ~65us). R10: packed
// FP32 (v_pk_fma_f32 via ext_vector float2) processes 2 modes per register
// pair -> 1.5 VALU ops per mode-sample (was 3). Tables pair-interleaved
// (re0,re1,im0,im1); Chebyshev x_{j+1} = 2Re(W) x_j - |W|^2 x_{j-1} on v2f.
// BLK=512, mode-split across 2 wave-groups, J=16, 32 waves/CU.

typedef float v2f __attribute__((ext_vector_type(2)));

static __device__ __forceinline__ float2 cmul(float2 a, float2 b) {
    return make_float2(fmaf(a.x, b.x, -(a.y * b.y)),
                       fmaf(a.x, b.y,   a.y * b.x));
}

template <int N2, int CPB, int J>
__global__ __launch_bounds__(2 * CPB, 8) void s4d_kernel(
    const float* __restrict__ C,
    const float* __restrict__ log_dt,
    const float* __restrict__ log_A_real,
    const float* __restrict__ A_imag,
    float* __restrict__ K,
    int L)
{
    constexpr int NP  = N2 / 2;          // mode pairs (16)
    constexpr int PPG = NP / 2;          // pairs per wave-group (8)
    __shared__ float4 s_loA[NP][16];     // (re0,re1,im0,im1): lo  = 2Cc*w^(lbase+k)
    __shared__ float4 s_loB[NP][16];     // (re0,re1,im0,im1): lo*W
    __shared__ float4 s_hiq[NP][16];     // (re0,re1,im0,im1): (w^16)^k
    __shared__ float4 s_ab [NP];         // (aW0,aW1,bW0,bW1)
    __shared__ float  s_part[J][CPB];    // group-1 partial sums (16 KB)

    const int h = blockIdx.x;
    const int y = blockIdx.y;
    const int lbase = y * (CPB * J);
    const int t = threadIdx.x;

    // ---- Parallel setup: thread t (0..511) builds entry (n = t>>4, k = t&15) ----
    {
        const int n   = t >> 4;          // 0..31
        const int k   = t & 15;
        const int p   = n >> 1;          // pair index
        const int c01 = n & 1;           // slot within pair

        const float dt  = expf(log_dt[h]);
        const float Are = -expf(log_A_real[h * N2 + n]);
        const float Aim = A_imag[h * N2 + n];
        const float dre = Are * dt;
        const float dim = Aim * dt;      // |dim| <= ~9.7 rad: fast sincos path
        float sw, cw;
        sincosf(dim, &sw, &cw);
        const float er = expf(dre);
        const float2 w = make_float2(er * cw, er * sw);
        // 2*Cc = 2*C*(w-1)/A
        const float nre = w.x - 1.0f;
        const float nim = w.y;
        const float inv = 1.0f / (Are * Are + Aim * Aim);
        const float cc  = 2.0f * C[h * N2 + n];
        const float2 c  = make_float2(cc * ((nre * Are + nim * Aim) * inv),
                                      cc * ((nim * Are - nre * Aim) * inv));
        // powers of w by squaring
        const float2 w2   = cmul(w,    w);
        const float2 w4   = cmul(w2,   w2);
        const float2 w8   = cmul(w4,   w4);
        const float2 w16  = cmul(w8,   w8);
        const float2 w32  = cmul(w16,  w16);
        const float2 w64  = cmul(w32,  w32);
        const float2 w128 = cmul(w64,  w64);
        const float2 W    = cmul(w128, w128);   // w^256 == w^CPB
        const float aW = W.x + W.x;
        const float bW = -fmaf(W.x, W.x, W.y * W.y);

        const float2 ONE = make_float2(1.0f, 0.0f);
        // w^k, k<16: product of selected {w,w2,w4,w8}
        float2 pk = (k & 1) ? w : ONE;
        pk = cmul(pk, (k & 2) ? w2 : ONE);
        pk = cmul(pk, (k & 4) ? w4 : ONE);
        pk = cmul(pk, (k & 8) ? w8 : ONE);
        // (w^16)^k: product of selected {w16,w32,w64,w128}
        float2 qk = (k & 1) ? w16 : ONE;
        qk = cmul(qk, (k & 2) ? w32  : ONE);
        qk = cmul(qk, (k & 4) ? w64  : ONE);
        qk = cmul(qk, (k & 8) ? w128 : ONE);

        // w^lbase = W^(J*y), block-uniform binary pow (no-op when y==0)
        float2 P = ONE;
        {
            float2 base = W;
            int ee = J * y;
            while (ee) { if (ee & 1) P = cmul(P, base); base = cmul(base, base); ee >>= 1; }
        }

        const float2 lo  = cmul(cmul(c, P), pk);   // 2Cc * w^(lbase+k)
        const float2 lo2 = cmul(lo, W);

        // Pair-interleaved scalar writes (even/odd n hit disjoint components)
        float* pA = (float*)&s_loA[p][k];
        float* pB = (float*)&s_loB[p][k];
        float* pH = (float*)&s_hiq[p][k];
        pA[c01] = lo.x;   pA[2 + c01] = lo.y;
        pB[c01] = lo2.x;  pB[2 + c01] = lo2.y;
        pH[c01] = qk.x;   pH[2 + c01] = qk.y;
        if (k == 0) {
            float* pC = (float*)&s_ab[p];
            pC[c01] = aW; pC[2 + c01] = bW;
        }
    }
    __syncthreads();

    v2f acc[J];
#pragma unroll
    for (int j = 0; j < J; ++j) acc[j] = (v2f){0.0f, 0.0f};

    const int col = t & (CPB - 1);       // sample column 0..255
    const int g   = t / CPB;             // wave-group 0/1
    const int tlo = col & 15;
    const int thi = col >> 4;
    const int pb  = g * PPG;

    for (int pp = 0; pp < PPG; ++pp) {
        const float4 la = s_loA[pb + pp][tlo];
        const float4 lb = s_loB[pb + pp][tlo];
        const float4 hq = s_hiq[pb + pp][thi];
        const float4 ab = s_ab [pb + pp];

        const v2f lre  = {la.x, la.y}, lim  = {la.z, la.w};
        const v2f l2re = {lb.x, lb.y}, l2im = {lb.z, lb.w};
        const v2f hre  = {hq.x, hq.y}, him  = {hq.z, hq.w};
        const v2f aw   = {ab.x, ab.y}, bw   = {ab.z, ab.w};

        v2f x0 = lre  * hre - lim  * him;   // Re(2Cc w^(lbase+col)) per mode
        v2f x1 = l2re * hre - l2im * him;   // Re(... * W)
        acc[0] += x0;
        acc[1] += x1;
#pragma unroll
        for (int j = 2; j < J; ++j) {
            const v2f x2 = aw * x1 + bw * x0;   // 2Re(W)x1 - |W|^2 x0 (pk_mul+pk_fma)
            acc[j] += x2;
            x0 = x1;
            x1 = x2;
        }
    }

    // ---- Cross-group reduction + store ----
    if (g == 1) {
#pragma unroll
        for (int j = 0; j < J; ++j) s_part[j][col] = acc[j].x + acc[j].y;
    }
    __syncthreads();
    if (g == 0) {
        float* __restrict__ outp = K + (size_t)h * (size_t)L + lbase + col;
#pragma unroll
        for (int j = 0; j < J; ++j) {
            const float r = acc[j].x + acc[j].y + s_part[j][col];
            const int l = lbase + j * CPB + col;
            if (l < L) outp[(size_t)j * CPB] = r;
        }
    }
}

extern "C" void kernel_launch(void* const* d_in, const int* in_sizes, int n_in,
                              void* d_out, int out_size, void* d_ws, size_t ws_size,
                              hipStream_t stream)
{
    const float* C          = (const float*)d_in[0];
    const float* log_dt     = (const float*)d_in[1];
    const float* log_A_real = (const float*)d_in[2];
    const float* A_imag     = (const float*)d_in[3];
    float* K = (float*)d_out;

    const int H   = in_sizes[1];           // 1024
    const int N2v = in_sizes[0] / H;       // 32
    const int L   = out_size / H;          // 4096
    constexpr int CPB = 256;               // sample columns per block
    constexpr int J   = 16;                // samples per column per block
    const int gy = (L + CPB * J - 1) / (CPB * J);   // 1 for L=4096

    if (N2v != 32) return;
    dim3 grid((unsigned)H, (unsigned)gy);
    s4d_kernel<32, CPB, J><<<grid, 2 * CPB, 0, stream>>>(
        C, log_dt, log_A_real, A_imag, K, L);
}